// Round 3
// baseline (560.179 us; speedup 1.0000x reference)
//
#include <hip/hip_runtime.h>
#include <math.h>

#define DEV __device__ __forceinline__

constexpr int BATCH = 8;
constexpr int LL    = 4096;   // H*W
constexpr int DM    = 96;     // d_model
constexpr int DI    = 192;    // d_inner
constexpr int KK    = 4;      // scan directions
constexpr int NS    = 16;     // d_state
constexpr int RR    = 6;      // dt_rank
constexpr int NC    = 64;     // chunks per scan
constexpr int CHUNK = 64;     // L / NC
constexpr int SUB   = 32;     // staging sub-block
constexpr int PST   = 40;     // padded proj row stride (6 dt | pad2 | 16 B | 16 C)
constexpr float L2E = 1.44269504088896340736f;
constexpr float LN2 = 0.69314718055994530942f;

DEV float fsilu(float x){ return x / (1.f + __expf(-x)); }
DEV float fsoftplus(float x){
  float t = exp2f(x * L2E);
  float r = log2f(1.f + t) * LN2;
  return (x > 15.f) ? x : r;
}

// physical pixel geometry per direction within an aligned 64-step chunk:
//   k=0: p0=cc*64, ps=+1   k=1: p0=cc, ps=+64
//   k=2: p0=4095-cc*64, ps=-1   k=3: p0=4095-cc, ps=-64
DEV void dir_geom(int k, int cc, int& p0, int& ps){
  if (k == 0){ p0 = cc * CHUNK;             ps = 1;   }
  else if (k == 1){ p0 = cc;                ps = 64;  }
  else if (k == 2){ p0 = (LL-1) - cc*CHUNK; ps = -1;  }
  else { p0 = (LL-1) - cc;                  ps = -64; }
}

// ---------------------------------------------------------------- in_proj GEMM
constexpr int IP_KC = 24;
__global__ __launch_bounds__(256) void k_inproj(
    const float* __restrict__ x, const float* __restrict__ Wi,
    float* __restrict__ xa, float* __restrict__ zs)
{
  __shared__ float xt[96][36];
  __shared__ float wl[384][IP_KC + 1];
  const int g0  = blockIdx.x * 32;
  const int tid = threadIdx.x;
  const int jg  = tid & 31;
  const int pg  = tid >> 5;

  float acc[4][12];
#pragma unroll
  for (int a = 0; a < 4; ++a)
#pragma unroll
    for (int i = 0; i < 12; ++i) acc[a][i] = 0.f;

  for (int idx = tid; idx < 32 * 96; idx += 256){
    int k = idx % 96, p = idx / 96;
    xt[k][p] = x[(size_t)(g0 + p) * 96 + k];
  }
  for (int kc = 0; kc < 96; kc += IP_KC){
    for (int idx = tid; idx < 384 * IP_KC; idx += 256){
      int kk = idx % IP_KC, j = idx / IP_KC;
      wl[j][kk] = Wi[(size_t)j * 96 + kc + kk];
    }
    __syncthreads();
#pragma unroll
    for (int kk = 0; kk < IP_KC; ++kk){
      const float4 xv = *(const float4*)&xt[kc + kk][pg * 4];
      float w[12];
#pragma unroll
      for (int i = 0; i < 12; ++i) w[i] = wl[jg + 32 * i][kk];
#pragma unroll
      for (int i = 0; i < 12; ++i){
        acc[0][i] = __builtin_fmaf(xv.x, w[i], acc[0][i]);
        acc[1][i] = __builtin_fmaf(xv.y, w[i], acc[1][i]);
        acc[2][i] = __builtin_fmaf(xv.z, w[i], acc[2][i]);
        acc[3][i] = __builtin_fmaf(xv.w, w[i], acc[3][i]);
      }
    }
    __syncthreads();
  }
#pragma unroll
  for (int pp = 0; pp < 4; ++pp){
    const int p = g0 + pg * 4 + pp;
#pragma unroll
    for (int i = 0; i < 12; ++i){
      const int j = jg + 32 * i;
      const float v = acc[pp][i];
      if (j < DI) xa[(size_t)p * DI + j] = v;
      else        zs[(size_t)p * DI + (j - DI)] = fsilu(v);
    }
  }
}

// ---------------------------------------------------------------- depthwise 3x3 conv + silu
__global__ __launch_bounds__(256) void k_conv(
    const float* __restrict__ xa, const float* __restrict__ cw,
    const float* __restrict__ cb, float* __restrict__ xc)
{
  const int gid = blockIdx.x * 256 + threadIdx.x;
  const int d4 = gid % 48;
  const int p  = (gid / 48) & (LL - 1);
  const int b  = gid / (48 * LL);
  const int d0 = d4 * 4;
  const int hh = p >> 6, wp = p & 63;

  float wg0[9], wg1[9], wg2[9], wg3[9];
#pragma unroll
  for (int j = 0; j < 9; ++j){
    wg0[j] = cw[(d0 + 0) * 9 + j];
    wg1[j] = cw[(d0 + 1) * 9 + j];
    wg2[j] = cw[(d0 + 2) * 9 + j];
    wg3[j] = cw[(d0 + 3) * 9 + j];
  }
  float a0 = cb[d0], a1 = cb[d0 + 1], a2 = cb[d0 + 2], a3 = cb[d0 + 3];
  const float* base = xa + (size_t)b * LL * DI + d0;
#pragma unroll
  for (int dy = 0; dy < 3; ++dy){
    const int hy = hh + dy - 1;
    if ((unsigned)hy >= 64u) continue;
#pragma unroll
    for (int dx = 0; dx < 3; ++dx){
      const int wx = wp + dx - 1;
      if ((unsigned)wx >= 64u) continue;
      const float4 v = *(const float4*)(base + (size_t)(hy * 64 + wx) * DI);
      const int j = dy * 3 + dx;
      a0 = __builtin_fmaf(v.x, wg0[j], a0);
      a1 = __builtin_fmaf(v.y, wg1[j], a1);
      a2 = __builtin_fmaf(v.z, wg2[j], a2);
      a3 = __builtin_fmaf(v.w, wg3[j], a3);
    }
  }
  float4 o; o.x = fsilu(a0); o.y = fsilu(a1); o.z = fsilu(a2); o.w = fsilu(a3);
  *(float4*)(xc + ((size_t)b * LL + p) * DI + d0) = o;
}

// ---------------------------------------------------------------- x_proj (4 dirs fused) -> scan-order projS
constexpr int XP_KC = 32;
__global__ __launch_bounds__(256) void k_xproj(
    const float* __restrict__ xc, const float* __restrict__ Wp, float* __restrict__ projS)
{
  __shared__ float xl[XP_KC][68];
  __shared__ float wl[XP_KC][161];
  const int b   = blockIdx.x / (LL / 64);
  const int p0  = (blockIdx.x % (LL / 64)) * 64;
  const int tid = threadIdx.x;
  const int cg  = tid & 15;
  const int pg  = tid >> 4;

  float acc[4][10];
#pragma unroll
  for (int a = 0; a < 4; ++a)
#pragma unroll
    for (int i = 0; i < 10; ++i) acc[a][i] = 0.f;

  for (int dd0 = 0; dd0 < DI; dd0 += XP_KC){
    __syncthreads();
    for (int idx = tid; idx < 8 * 64; idx += 256){
      int q = idx & 7, p = idx >> 3;
      const float4 v = *(const float4*)&xc[((size_t)b * LL + p0 + p) * DI + dd0 + q * 4];
      xl[q * 4 + 0][p] = v.x; xl[q * 4 + 1][p] = v.y;
      xl[q * 4 + 2][p] = v.z; xl[q * 4 + 3][p] = v.w;
    }
    for (int idx = tid; idx < XP_KC * 160; idx += 256){
      int kk = idx & 31, c2 = idx >> 5;
      int k = c2 / 40, c = c2 % 40;
      wl[kk][c2] = (c < 38) ? Wp[(size_t)(k * 38 + c) * DI + dd0 + kk] : 0.f;
    }
    __syncthreads();
#pragma unroll
    for (int kk = 0; kk < XP_KC; ++kk){
      const float4 xv = *(const float4*)&xl[kk][pg * 4];
      float w[10];
#pragma unroll
      for (int i = 0; i < 10; ++i) w[i] = wl[kk][cg + 16 * i];
#pragma unroll
      for (int i = 0; i < 10; ++i){
        acc[0][i] = __builtin_fmaf(xv.x, w[i], acc[0][i]);
        acc[1][i] = __builtin_fmaf(xv.y, w[i], acc[1][i]);
        acc[2][i] = __builtin_fmaf(xv.z, w[i], acc[2][i]);
        acc[3][i] = __builtin_fmaf(xv.w, w[i], acc[3][i]);
      }
    }
  }
#pragma unroll
  for (int i = 0; i < 10; ++i){
    const int c2 = cg + 16 * i;
    const int k = c2 / 40, c = c2 % 40;
    if (c < 38){
      const int off = c + (c >= 6 ? 2 : 0);
#pragma unroll
      for (int pp = 0; pp < 4; ++pp){
        const int p = p0 + pg * 4 + pp;
        const int hh = p >> 6, ww = p & 63;
        int l;
        if (k == 0)      l = p;
        else if (k == 1) l = ww * 64 + hh;
        else if (k == 2) l = (LL - 1) - p;
        else             l = (LL - 1) - (ww * 64 + hh);
        projS[((size_t)(b * KK + k) * LL + l) * PST + off] = acc[pp][i];
      }
    }
  }
}

// ---------------------------------------------------------------- scan step helpers (rows in LDS)
DEV float scan_dt(const float* __restrict__ row, const float* wdt, float bias){
  const float4 q0 = *(const float4*)(row + 0);
  const float2 q1 = *(const float2*)(row + 4);
  float dr = bias + q0.x * wdt[0] + q0.y * wdt[1] + q0.z * wdt[2]
                  + q0.w * wdt[3] + q1.x * wdt[4] + q1.y * wdt[5];
  return fsoftplus(dr);
}

DEV void scan_step_p1(const float* __restrict__ row, float u,
                      const float* wdt, float bias, const float* A2,
                      float* h, float& sdl)
{
  const float dl = scan_dt(row, wdt, bias);
  sdl += dl;
  const float du = dl * u;
#pragma unroll
  for (int q = 0; q < 4; ++q){
    const float4 Bq = *(const float4*)(row + 8 + q * 4);
    h[4*q+0] = __builtin_fmaf(exp2f(dl * A2[4*q+0]), h[4*q+0], Bq.x * du);
    h[4*q+1] = __builtin_fmaf(exp2f(dl * A2[4*q+1]), h[4*q+1], Bq.y * du);
    h[4*q+2] = __builtin_fmaf(exp2f(dl * A2[4*q+2]), h[4*q+2], Bq.z * du);
    h[4*q+3] = __builtin_fmaf(exp2f(dl * A2[4*q+3]), h[4*q+3], Bq.w * du);
  }
}

DEV float scan_step_p2(const float* __restrict__ row, float u,
                       const float* wdt, float bias, const float* A2,
                       float dsv, float* h)
{
  const float dl = scan_dt(row, wdt, bias);
  const float du = dl * u;
  float y = dsv * u;
#pragma unroll
  for (int q = 0; q < 4; ++q){
    const float4 Bq = *(const float4*)(row + 8  + q * 4);
    const float4 Cq = *(const float4*)(row + 24 + q * 4);
    float hv;
    hv = __builtin_fmaf(exp2f(dl * A2[4*q+0]), h[4*q+0], Bq.x * du); h[4*q+0] = hv; y = __builtin_fmaf(hv, Cq.x, y);
    hv = __builtin_fmaf(exp2f(dl * A2[4*q+1]), h[4*q+1], Bq.y * du); h[4*q+1] = hv; y = __builtin_fmaf(hv, Cq.y, y);
    hv = __builtin_fmaf(exp2f(dl * A2[4*q+2]), h[4*q+2], Bq.z * du); h[4*q+2] = hv; y = __builtin_fmaf(hv, Cq.z, y);
    hv = __builtin_fmaf(exp2f(dl * A2[4*q+3]), h[4*q+3], Bq.w * du); h[4*q+3] = hv; y = __builtin_fmaf(hv, Cq.w, y);
  }
  return y;
}

// ---------------------------------------------------------------- pass1: per-chunk local scan (h0=0)
__global__ __launch_bounds__(192, 6) void k_pass1(
    const float* __restrict__ projS, const float* __restrict__ xc,
    const float* __restrict__ Wdt, const float* __restrict__ dtb,
    const float* __restrict__ Alog, float* __restrict__ Sh, float* __restrict__ Ssum)
{
  __shared__ float pb[SUB][PST];      // 5 KiB
  const int bid = blockIdx.x;          // 2048 = b(3)|k(2)|cc(6)
  const int cc = bid & (NC - 1);
  const int k  = (bid >> 6) & 3;
  const int b  = bid >> 8;
  const int d  = threadIdx.x;
  const int kd = k * DI + d;

  float A2[NS];
#pragma unroll
  for (int n = 0; n < NS; ++n) A2[n] = -__expf(Alog[(size_t)kd * NS + n]) * L2E;
  float wdt[RR];
#pragma unroll
  for (int r = 0; r < RR; ++r) wdt[r] = Wdt[kd * RR + r];
  const float bias = dtb[kd];

  int p0, ps; dir_geom(k, cc, p0, ps);
  const float4* pr = (const float4*)(projS + ((size_t)(b * KK + k) * LL + cc * CHUNK) * PST);
  const float* ub  = xc + (size_t)b * LL * DI + (size_t)p0 * DI + d;
  const ptrdiff_t ust = (ptrdiff_t)ps * DI;

  float uring[4];
#pragma unroll
  for (int i = 0; i < 4; ++i) uring[i] = ub[ust * i];
  const float* ut = ub + ust * 4;

  float h[NS];
#pragma unroll
  for (int n = 0; n < NS; ++n) h[n] = 0.f;
  float sdl = 0.f;

  for (int sb = 0; sb < CHUNK / SUB; ++sb){
    __syncthreads();
    for (int idx = d; idx < SUB * (PST / 4); idx += DI)
      ((float4*)pb)[idx] = pr[sb * (SUB * PST / 4) + idx];
    __syncthreads();
#pragma unroll 2
    for (int s = 0; s < SUB; ++s){
      const float u = uring[s & 3];
      uring[s & 3] = *ut; ut += ust;          // harmless over-read past chunk
      scan_step_p1(pb[s], u, wdt, bias, A2, h, sdl);
    }
  }

  float* shp = Sh + ((size_t)((b * KK + k) * NC + cc) * DI + d) * NS;
#pragma unroll
  for (int n = 0; n < NS; ++n) shp[n] = h[n];
  Ssum[(size_t)((b * KK + k) * NC + cc) * DI + d] = sdl;
}

// ---------------------------------------------------------------- chunk-prefix (in-place Sh -> H0)
__global__ __launch_bounds__(256) void k_prefix(
    float* __restrict__ ShH0, const float* __restrict__ Ssum, const float* __restrict__ Alog)
{
  const int gid = blockIdx.x * 256 + threadIdx.x;     // 32*192*16 = 98304
  const int n  = gid & 15;
  const int d  = (gid >> 4) % DI;
  const int bk = gid / (16 * DI);
  const float A = -__expf(Alog[(size_t)((bk & 3) * DI + d) * NS + n]);
  float h0 = 0.f;
  for (int c = 0; c < NC; ++c){
    const size_t ix = ((size_t)(bk * NC + c) * DI + d) * NS + n;
    const float sh = ShH0[ix];
    const float P  = __expf(Ssum[(size_t)(bk * NC + c) * DI + d] * A);
    ShH0[ix] = h0;
    h0 = __builtin_fmaf(P, h0, sh);
  }
}

// ---------------------------------------------------------------- pass2: fused dual-direction scan
// Block (b, pair, cc) owns pixel line of dirs {pair, pair+2}:
//   fwd = dir pair, chunk cc; bwd = dir pair+2, chunk 63-cc — same 64 pixels, opposite order.
// First 32 steps first-touch every row ("="), last 32 steps accumulate ("+=", same thread).
__global__ __launch_bounds__(192, 3) void k_pass2(
    const float* __restrict__ projS, const float* __restrict__ xc,
    const float* __restrict__ Wdt, const float* __restrict__ dtb,
    const float* __restrict__ Alog, const float* __restrict__ DsP,
    const float* __restrict__ H0, float* __restrict__ yA, float* __restrict__ yB)
{
  __shared__ float pbF[SUB][PST];     // 5 KiB
  __shared__ float pbB[SUB][PST];     // 5 KiB
  const int bid  = blockIdx.x;        // 1024 = b(3)|pair(1)|cc(6)
  const int cc   = bid & (NC - 1);
  const int pair = (bid >> 6) & 1;
  const int b    = bid >> 7;
  const int ccb  = NC - 1 - cc;
  const int kf = pair, kb = pair + 2;
  const int d  = threadIdx.x;
  const int kdF = kf * DI + d, kdB = kb * DI + d;
  float* yX = pair ? yB : yA;

  float A2F[NS], A2B[NS];
#pragma unroll
  for (int n = 0; n < NS; ++n){
    A2F[n] = -__expf(Alog[(size_t)kdF * NS + n]) * L2E;
    A2B[n] = -__expf(Alog[(size_t)kdB * NS + n]) * L2E;
  }
  float wdtF[RR], wdtB[RR];
#pragma unroll
  for (int r = 0; r < RR; ++r){
    wdtF[r] = Wdt[kdF * RR + r];
    wdtB[r] = Wdt[kdB * RR + r];
  }
  const float biasF = dtb[kdF], biasB = dtb[kdB];
  const float dsF = DsP[kdF],  dsB = DsP[kdB];

  float hf[NS], hb[NS];
  {
    const float* h0f = H0 + ((size_t)((b * KK + kf) * NC + cc)  * DI + d) * NS;
    const float* h0b = H0 + ((size_t)((b * KK + kb) * NC + ccb) * DI + d) * NS;
#pragma unroll
    for (int n = 0; n < NS; ++n){ hf[n] = h0f[n]; hb[n] = h0b[n]; }
  }

  int p0f, psf; dir_geom(kf, cc,  p0f, psf);
  int p0b, psb; dir_geom(kb, ccb, p0b, psb);
  const float4* prF = (const float4*)(projS + ((size_t)(b * KK + kf) * LL + cc  * CHUNK) * PST);
  const float4* prB = (const float4*)(projS + ((size_t)(b * KK + kb) * LL + ccb * CHUNK) * PST);
  const float* ubf = xc + (size_t)b * LL * DI + (size_t)p0f * DI + d;
  const float* ubb = xc + (size_t)b * LL * DI + (size_t)p0b * DI + d;
  float* ypf = yX + (size_t)b * LL * DI + (size_t)p0f * DI + d;
  float* ypb = yX + (size_t)b * LL * DI + (size_t)p0b * DI + d;
  const ptrdiff_t ustf = (ptrdiff_t)psf * DI;
  const ptrdiff_t ustb = (ptrdiff_t)psb * DI;

  float urf[4], urb[4];
#pragma unroll
  for (int i = 0; i < 4; ++i){ urf[i] = ubf[ustf * i]; urb[i] = ubb[ustb * i]; }
  const float* utf = ubf + ustf * 4;
  const float* utb = ubb + ustb * 4;

  for (int sb = 0; sb < 2; ++sb){
    __syncthreads();
    for (int idx = d; idx < SUB * (PST / 4); idx += DI){
      ((float4*)pbF)[idx] = prF[sb * (SUB * PST / 4) + idx];
      ((float4*)pbB)[idx] = prB[sb * (SUB * PST / 4) + idx];
    }
    __syncthreads();
#pragma unroll 2
    for (int s = 0; s < SUB; ++s){
      const float uF = urf[s & 3];
      const float uB = urb[s & 3];
      urf[s & 3] = *utf; utf += ustf;
      urb[s & 3] = *utb; utb += ustb;
      const float yF = scan_step_p2(pbF[s], uF, wdtF, biasF, A2F, dsF, hf);
      const float yB2 = scan_step_p2(pbB[s], uB, wdtB, biasB, A2B, dsB, hb);
      if (sb == 0){ *ypf = yF; *ypb = yB2; }
      else        { *ypf += yF; *ypb += yB2; }
      ypf += ustf; ypb += ustb;
    }
  }
}

// ---------------------------------------------------------------- merge + LayerNorm + silu(z) gate
__global__ __launch_bounds__(256) void k_mergeln(
    const float* __restrict__ yA, const float* __restrict__ yB,
    const float* __restrict__ zs, const float* __restrict__ wn,
    const float* __restrict__ bn, float* __restrict__ t)
{
  const int g = blockIdx.x * 4 + (threadIdx.x >> 6);
  const int lane = threadIdx.x & 63;
  const float* ya = yA + (size_t)g * DI;
  const float* yb = yB + (size_t)g * DI;
  const float* zr = zs + (size_t)g * DI;
  float* tr = t + (size_t)g * DI;

  const float v0 = ya[lane]       + yb[lane];
  const float v1 = ya[lane + 64]  + yb[lane + 64];
  const float v2 = ya[lane + 128] + yb[lane + 128];
  float s1 = v0 + v1 + v2;
  float s2 = v0 * v0 + v1 * v1 + v2 * v2;
#pragma unroll
  for (int off = 32; off > 0; off >>= 1){
    s1 += __shfl_xor(s1, off);
    s2 += __shfl_xor(s2, off);
  }
  const float mu  = s1 * (1.f / DI);
  const float var = s2 * (1.f / DI) - mu * mu;
  const float rs  = rsqrtf(var + 1e-5f);
  tr[lane]       = ((v0 - mu) * rs * wn[lane]       + bn[lane])       * zr[lane];
  tr[lane + 64]  = ((v1 - mu) * rs * wn[lane + 64]  + bn[lane + 64])  * zr[lane + 64];
  tr[lane + 128] = ((v2 - mu) * rs * wn[lane + 128] + bn[lane + 128]) * zr[lane + 128];
}

// ---------------------------------------------------------------- out_proj GEMM (32768x96x192)
__global__ __launch_bounds__(256) void k_outproj(
    const float* __restrict__ t, const float* __restrict__ Wo, float* __restrict__ out)
{
  __shared__ float xl[32][36];
  __shared__ float wl[96][33];
  const int g0  = blockIdx.x * 32;
  const int tid = threadIdx.x;
  const int jg  = tid & 31;
  const int pg  = tid >> 5;

  float acc[4][3];
#pragma unroll
  for (int a = 0; a < 4; ++a){ acc[a][0]=0.f; acc[a][1]=0.f; acc[a][2]=0.f; }

  for (int kc = 0; kc < DI; kc += 32){
    __syncthreads();
    for (int idx = tid; idx < 8 * 32; idx += 256){
      int q = idx & 7, p = idx >> 3;
      const float4 v = *(const float4*)&t[(size_t)(g0 + p) * DI + kc + q * 4];
      xl[q * 4 + 0][p] = v.x; xl[q * 4 + 1][p] = v.y;
      xl[q * 4 + 2][p] = v.z; xl[q * 4 + 3][p] = v.w;
    }
    for (int idx = tid; idx < 96 * 32; idx += 256){
      int kk = idx & 31, j = idx >> 5;
      wl[j][kk] = Wo[(size_t)j * DI + kc + kk];
    }
    __syncthreads();
#pragma unroll
    for (int kk = 0; kk < 32; ++kk){
      const float4 xv = *(const float4*)&xl[kk][pg * 4];
      const float w0 = wl[jg][kk], w1 = wl[jg + 32][kk], w2 = wl[jg + 64][kk];
      acc[0][0] = __builtin_fmaf(xv.x, w0, acc[0][0]);
      acc[0][1] = __builtin_fmaf(xv.x, w1, acc[0][1]);
      acc[0][2] = __builtin_fmaf(xv.x, w2, acc[0][2]);
      acc[1][0] = __builtin_fmaf(xv.y, w0, acc[1][0]);
      acc[1][1] = __builtin_fmaf(xv.y, w1, acc[1][1]);
      acc[1][2] = __builtin_fmaf(xv.y, w2, acc[1][2]);
      acc[2][0] = __builtin_fmaf(xv.z, w0, acc[2][0]);
      acc[2][1] = __builtin_fmaf(xv.z, w1, acc[2][1]);
      acc[2][2] = __builtin_fmaf(xv.z, w2, acc[2][2]);
      acc[3][0] = __builtin_fmaf(xv.w, w0, acc[3][0]);
      acc[3][1] = __builtin_fmaf(xv.w, w1, acc[3][1]);
      acc[3][2] = __builtin_fmaf(xv.w, w2, acc[3][2]);
    }
  }
#pragma unroll
  for (int pp = 0; pp < 4; ++pp){
    const int p = g0 + pg * 4 + pp;
    out[(size_t)p * DM + jg]      = acc[pp][0];
    out[(size_t)p * DM + jg + 32] = acc[pp][1];
    out[(size_t)p * DM + jg + 64] = acc[pp][2];
  }
}

// ---------------------------------------------------------------- launch
extern "C" void kernel_launch(void* const* d_in, const int* in_sizes, int n_in,
                              void* d_out, int out_size, void* d_ws, size_t ws_size,
                              hipStream_t stream)
{
  const float* x    = (const float*)d_in[0];
  const float* Wi   = (const float*)d_in[1];
  const float* cw   = (const float*)d_in[2];
  const float* cb   = (const float*)d_in[3];
  const float* Wp   = (const float*)d_in[4];
  const float* Wdt  = (const float*)d_in[5];
  const float* dtb  = (const float*)d_in[6];
  const float* Alog = (const float*)d_in[7];
  const float* DsP  = (const float*)d_in[8];
  const float* wn   = (const float*)d_in[9];
  const float* bn   = (const float*)d_in[10];
  const float* Wo   = (const float*)d_in[11];
  float* out = (float*)d_out;
  float* ws  = (float*)d_ws;

  constexpr size_t SZ_BLD = (size_t)BATCH * LL * DI;        // 6,291,456
  float* xa    = ws;                                        // reused as projS after conv
  float* projS = ws;
  float* zs    = ws + SZ_BLD;
  float* xc    = ws + 2 * SZ_BLD;                           // reused as t after pass2
  float* tbuf  = xc;
  float* ShH0  = ws + 3 * SZ_BLD;
  float* Ssum  = ws + 4 * SZ_BLD;
  float* yA    = ws + 4 * SZ_BLD + 393216;
  float* yB    = ws + 5 * SZ_BLD + 393216;

  k_inproj <<<(BATCH * LL) / 32, 256, 0, stream>>>(x, Wi, xa, zs);
  k_conv   <<<(BATCH * LL * 48) / 256, 256, 0, stream>>>(xa, cw, cb, xc);
  k_xproj  <<<BATCH * (LL / 64), 256, 0, stream>>>(xc, Wp, projS);
  k_pass1  <<<BATCH * KK * NC, 192, 0, stream>>>(projS, xc, Wdt, dtb, Alog, ShH0, Ssum);
  k_prefix <<<(32 * DI * NS) / 256, 256, 0, stream>>>(ShH0, Ssum, Alog);
  k_pass2  <<<BATCH * 2 * NC, 192, 0, stream>>>(projS, xc, Wdt, dtb, Alog, DsP, ShH0, yA, yB);
  k_mergeln<<<(BATCH * LL) / 4, 256, 0, stream>>>(yA, yB, zs, wn, bn, tbuf);
  k_outproj<<<(BATCH * LL) / 32, 256, 0, stream>>>(tbuf, Wo, out);
}